// Round 5
// baseline (314.936 us; speedup 1.0000x reference)
//
#include <hip/hip_runtime.h>
#include <math.h>

#define N_NODES 50000
#define N_EDGES 800000
#define IN_DIM 256
#define HID 128
#define ZPITCH 384   // [agg:0..128 | h:128..256 | h1:256..384]

typedef unsigned short u16;
typedef u16 u16x8 __attribute__((ext_vector_type(8)));
typedef u16 u16x2 __attribute__((ext_vector_type(2)));
typedef __bf16 bf16x8 __attribute__((ext_vector_type(8)));
typedef float f32x4 __attribute__((ext_vector_type(4)));

union F8 { u16x8 u; bf16x8 h; };

__device__ __forceinline__ u16 f2b(float f) {
    unsigned u = __builtin_bit_cast(unsigned, f);
    u = (u + 0x7FFFu + ((u >> 16) & 1u)) >> 16;   // RNE
    return (u16)u;
}
__device__ __forceinline__ float b2f(u16 h) {
    unsigned u = ((unsigned)h) << 16;
    return __builtin_bit_cast(float, u);
}

// ---------------------------------------------------------------------------
// Unified bf16 MFMA GEMM: C[M,128] = act(A[M,K] @ Wf + bias0 (+bias1))
// BM=64/block (4 waves, each wave ONE 16-row M-frag x 8 N-frags) -> 782 blocks,
// ~12 waves/CU: latency hidden by TLP instead of per-wave ILP.
// ---------------------------------------------------------------------------
template<int A_F32>
__device__ __forceinline__ F8 load_a(const void* base, size_t row, int P, int koff)
{
    F8 r;
    if (A_F32) {
        const float* p = (const float*)base + row * P + koff;
        float4 f0 = *reinterpret_cast<const float4*>(p);
        float4 f1 = *reinterpret_cast<const float4*>(p + 4);
        r.h[0] = (__bf16)f0.x; r.h[1] = (__bf16)f0.y;
        r.h[2] = (__bf16)f0.z; r.h[3] = (__bf16)f0.w;
        r.h[4] = (__bf16)f1.x; r.h[5] = (__bf16)f1.y;
        r.h[6] = (__bf16)f1.z; r.h[7] = (__bf16)f1.w;
    } else {
        r.u = *reinterpret_cast<const u16x8*>((const u16*)base + row * P + koff);
    }
    return r;
}

template<int LEAKY, int STATS, int OUT_BF16, int A_F32>
__global__ __launch_bounds__(256) void gemm_mfma(
    int M, const void* __restrict__ A, int P, int K,
    const u16* __restrict__ Wf,
    const float* __restrict__ bias0, const float* __restrict__ bias1,
    void* __restrict__ Cout, int CP,
    float* __restrict__ stats)
{
    const int t   = threadIdx.x;
    const int w   = t >> 6;
    const int l   = t & 63;
    const int l15 = l & 15;
    const int lg  = l >> 4;
    const int rb  = blockIdx.x * 64 + w * 16;

    int r0 = rb + l15;
    size_t r0c = (size_t)(r0 < M ? r0 : M - 1);
    const int ko = lg * 8;
    const u16* pb = Wf + l * 8;

    f32x4 acc[8];
#pragma unroll
    for (int j = 0; j < 8; ++j) acc[j] = 0.0f;

    F8 a0, b[8];
    a0 = load_a<A_F32>(A, r0c, P, ko);
#pragma unroll
    for (int j = 0; j < 8; ++j) b[j].u = *(const u16x8*)(pb + j * 512);

    const int NC = K >> 5;
    for (int c = 1; c < NC; ++c) {
        F8 na0, nb[8];
        na0 = load_a<A_F32>(A, r0c, P, c * 32 + ko);
#pragma unroll
        for (int j = 0; j < 8; ++j) nb[j].u = *(const u16x8*)(pb + c * 4096 + j * 512);
#pragma unroll
        for (int j = 0; j < 8; ++j)
            acc[j] = __builtin_amdgcn_mfma_f32_16x16x32_bf16(a0.h, b[j].h, acc[j], 0, 0, 0);
        a0 = na0;
#pragma unroll
        for (int j = 0; j < 8; ++j) b[j] = nb[j];
    }
#pragma unroll
    for (int j = 0; j < 8; ++j)
        acc[j] = __builtin_amdgcn_mfma_f32_16x16x32_bf16(a0.h, b[j].h, acc[j], 0, 0, 0);

    float bias_j[8];
#pragma unroll
    for (int j = 0; j < 8; ++j) {
        float bb = bias0[16 * j + l15];
        if (bias1) bb += bias1[16 * j + l15];
        bias_j[j] = bb;
    }

    float csum[8], csq[8];
#pragma unroll
    for (int j = 0; j < 8; ++j) { csum[j] = 0.f; csq[j] = 0.f; }

    {
        int rbase = rb + lg * 4;
#pragma unroll
        for (int r = 0; r < 4; ++r) {
            int row = rbase + r;
            bool ok = row < M;
#pragma unroll
            for (int j = 0; j < 8; ++j) {
                float y = acc[j][r] + bias_j[j];
                if (LEAKY) y = (y >= 0.f) ? y : 0.2f * y;
                if (ok) {
                    if (OUT_BF16)
                        ((u16*)Cout)[(size_t)row * CP + 16 * j + l15] = f2b(y);
                    else
                        ((float*)Cout)[(size_t)row * CP + 16 * j + l15] = y;
                    if (STATS) { csum[j] += y; csq[j] += y * y; }
                }
            }
        }
    }

    if (STATS) {
        __shared__ float sred[256];
        sred[t] = 0.f;
        __syncthreads();
#pragma unroll
        for (int j = 0; j < 8; ++j) {
            float s = csum[j];
            float q = csq[j];
            s += __shfl_xor(s, 16); s += __shfl_xor(s, 32);
            q += __shfl_xor(q, 16); q += __shfl_xor(q, 32);
            if (lg == 0) {
                atomicAdd(&sred[16 * j + l15], s);
                atomicAdd(&sred[128 + 16 * j + l15], q);
            }
        }
        __syncthreads();
        atomicAdd(&stats[t], sred[t]);
    }
}

// ---------------------------------------------------------------------------
// weight -> fragment-ordered bf16, with optional per-K-row scale (BN fold)
// ---------------------------------------------------------------------------
__global__ __launch_bounds__(256) void conv_w(const float* s0, const float* s1, const float* s2,
                                              const float* sc0, const float* sc1, const float* sc2,
                                              int rows_each, u16* __restrict__ dst, int nchunks)
{
    int tid = blockIdx.x * 256 + threadIdx.x;
    if (tid >= nchunks * 512) return;
    int c   = tid >> 9;
    int j   = (tid >> 6) & 7;
    int l   = tid & 63;
    int l15 = l & 15, lg = l >> 4;

    int srow0 = c * 32;
    int si    = srow0 / rows_each;
    const float* S  = (si == 0) ? s0 : (si == 1) ? s1 : s2;
    const float* SC = (si == 0) ? sc0 : (si == 1) ? sc1 : sc2;
    int rbase = srow0 - si * rows_each + lg * 8;
    int col   = 16 * j + l15;

    u16x8 o;
#pragma unroll
    for (int i = 0; i < 8; ++i) {
        float v = S[(size_t)(rbase + i) * HID + col];
        if (SC) v *= SC[rbase + i];
        o[i] = f2b(v);
    }
    reinterpret_cast<u16x8*>(dst)[tid] = o;
}

// bias fold: outb[j] = b0[j] (+b1[j]) + sum_i sh[i]*(W0[i][j] (+W1[i][j]))
__global__ void bias_fold(const float* __restrict__ b0, const float* __restrict__ b1,
                          const float* __restrict__ W0, const float* __restrict__ W1,
                          const float* __restrict__ sh, float* __restrict__ outb)
{
    int j = threadIdx.x;   // 128
    float acc = b0[j] + (b1 ? b1[j] : 0.f);
    for (int i = 0; i < HID; ++i) {
        float w = W0[(size_t)i * HID + j] + (W1 ? W1[(size_t)i * HID + j] : 0.f);
        acc = fmaf(sh[i], w, acc);
    }
    outb[j] = acc;
}

// ---------------------------------------------------------------------------
// BatchNorm params
// ---------------------------------------------------------------------------
__global__ void bn_params(const float* __restrict__ stats,
                          const float* __restrict__ gamma,
                          const float* __restrict__ beta,
                          float* __restrict__ scale,
                          float* __restrict__ shift, float invn)
{
    int j = threadIdx.x;
    float mean = stats[j] * invn;
    float var  = stats[128 + j] * invn - mean * mean;
    var = fmaxf(var, 0.f);
    float sc = gamma[j] / sqrtf(var + 1e-5f);
    scale[j] = sc;
    shift[j] = beta[j] - mean * sc;
}

// ---------------------------------------------------------------------------
// CSR build
// ---------------------------------------------------------------------------
__global__ __launch_bounds__(256) void edge_count(const int* __restrict__ dst, int* __restrict__ cnt)
{
    int e = blockIdx.x * 256 + threadIdx.x;
    if (e < N_EDGES) atomicAdd(&cnt[dst[e]], 1);
}

__global__ __launch_bounds__(256) void scan_block(const int* __restrict__ cnt,
                                                  int* __restrict__ excl,
                                                  int* __restrict__ bsum, int n)
{
    __shared__ int sh[256];
    int t = threadIdx.x;
    int i = blockIdx.x * 256 + t;
    int v = (i < n) ? cnt[i] : 0;
    sh[t] = v;
    __syncthreads();
#pragma unroll
    for (int off = 1; off < 256; off <<= 1) {
        int x = (t >= off) ? sh[t - off] : 0;
        __syncthreads();
        sh[t] += x;
        __syncthreads();
    }
    if (i < n) excl[i] = sh[t] - v;
    if (t == 255) bsum[blockIdx.x] = sh[255];
}

__global__ __launch_bounds__(256) void scan_bsum(int* __restrict__ bsum, int nb)
{
    __shared__ int sh[256];
    int t = threadIdx.x;
    int v = (t < nb) ? bsum[t] : 0;
    sh[t] = v;
    __syncthreads();
#pragma unroll
    for (int off = 1; off < 256; off <<= 1) {
        int x = (t >= off) ? sh[t - off] : 0;
        __syncthreads();
        sh[t] += x;
        __syncthreads();
    }
    if (t < nb) bsum[t] = sh[t] - v;   // exclusive
}

__global__ __launch_bounds__(256) void scan_add(int* __restrict__ row_ptr,
                                                int* __restrict__ fillrp,
                                                const int* __restrict__ bsum, int n)
{
    int i = blockIdx.x * 256 + threadIdx.x;
    if (i < n) {
        int v = row_ptr[i] + bsum[i >> 8];
        row_ptr[i] = v;
        fillrp[i]  = v;
    }
    if (i == 0) row_ptr[n] = N_EDGES;
}

// XCD-partitioned CSR fill (see R4 notes: keeps col_idx line writes XCD-local)
#define FILL_EPB 4096
__global__ __launch_bounds__(256) void edge_fill_part(const int* __restrict__ src,
                                                      const int* __restrict__ dst,
                                                      int* __restrict__ fillrp,
                                                      int* __restrict__ col_idx)
{
    const int range = blockIdx.x & 7;
    const int base  = (blockIdx.x >> 3) * FILL_EPB;
    const int lo = range * 6250, hi = lo + 6250;
#pragma unroll
    for (int k = 0; k < FILL_EPB / 256; ++k) {
        int e = base + k * 256 + threadIdx.x;
        if (e < N_EDGES) {
            int d = dst[e];
            if (d >= lo && d < hi) {
                int pos = atomicAdd(&fillrp[d], 1);
                col_idx[pos] = src[e];
            }
        }
    }
}

// ---------------------------------------------------------------------------
// SpMM mean over bf16 rows in Z. One wave per node, ushort2 per lane.
// ---------------------------------------------------------------------------
__global__ __launch_bounds__(256) void spmm_mean(const int* __restrict__ row_ptr,
                                                 const int* __restrict__ col_idx,
                                                 const u16* __restrict__ Z_in,
                                                 u16* __restrict__ Z_out)
{
    int node = blockIdx.x * 4 + (threadIdx.x >> 6);
    if (node >= N_NODES) return;
    int lane = threadIdx.x & 63;
    int beg = row_ptr[node];
    int end = row_ptr[node + 1];

    float sx = 0.f, sy = 0.f;
    int e = beg;
    for (; e + 4 <= end; e += 4) {
        int c0 = col_idx[e], c1 = col_idx[e + 1], c2 = col_idx[e + 2], c3 = col_idx[e + 3];
        u16x2 v0 = *reinterpret_cast<const u16x2*>(Z_in + (size_t)c0 * ZPITCH + lane * 2);
        u16x2 v1 = *reinterpret_cast<const u16x2*>(Z_in + (size_t)c1 * ZPITCH + lane * 2);
        u16x2 v2 = *reinterpret_cast<const u16x2*>(Z_in + (size_t)c2 * ZPITCH + lane * 2);
        u16x2 v3 = *reinterpret_cast<const u16x2*>(Z_in + (size_t)c3 * ZPITCH + lane * 2);
        sx += (b2f(v0[0]) + b2f(v1[0])) + (b2f(v2[0]) + b2f(v3[0]));
        sy += (b2f(v0[1]) + b2f(v1[1])) + (b2f(v2[1]) + b2f(v3[1]));
    }
    for (; e < end; ++e) {
        int c = col_idx[e];
        u16x2 v = *reinterpret_cast<const u16x2*>(Z_in + (size_t)c * ZPITCH + lane * 2);
        sx += b2f(v[0]); sy += b2f(v[1]);
    }
    float inv = 1.f / fmaxf((float)(end - beg), 1.f);
    u16x2 r; r[0] = f2b(sx * inv); r[1] = f2b(sy * inv);
    *reinterpret_cast<u16x2*>(Z_out + (size_t)node * ZPITCH + lane * 2) = r;
}

// ---------------------------------------------------------------------------
// Final: BN2 apply + L2 row-normalize, in place on d_out (fp32). One wave/row.
// ---------------------------------------------------------------------------
__global__ __launch_bounds__(256) void bn_rownorm(float* __restrict__ out,
                                                  const float* __restrict__ scale,
                                                  const float* __restrict__ shift)
{
    int row = blockIdx.x * 4 + (threadIdx.x >> 6);
    if (row >= N_NODES) return;
    int lane = threadIdx.x & 63;
    float2 v  = *reinterpret_cast<const float2*>(&out[(size_t)row * HID + lane * 2]);
    float2 sc = *reinterpret_cast<const float2*>(&scale[lane * 2]);
    float2 sh = *reinterpret_cast<const float2*>(&shift[lane * 2]);
    float y0 = v.x * sc.x + sh.x;
    float y1 = v.y * sc.y + sh.y;
    float ss = y0 * y0 + y1 * y1;
#pragma unroll
    for (int m = 1; m < 64; m <<= 1) ss += __shfl_xor(ss, m);
    float inv = 1.f / fmaxf(sqrtf(ss), 1e-12f);
    float2 r = {y0 * inv, y1 * inv};
    *reinterpret_cast<float2*>(&out[(size_t)row * HID + lane * 2]) = r;
}

// ---------------------------------------------------------------------------
extern "C" void kernel_launch(void* const* d_in, const int* in_sizes, int n_in,
                              void* d_out, int out_size, void* d_ws, size_t ws_size,
                              hipStream_t stream)
{
    const float* x     = (const float*)d_in[0];
    const int*   ei    = (const int*)d_in[1];
    const float* W_in  = (const float*)d_in[2];
    const float* b_in  = (const float*)d_in[3];
    const float* g1    = (const float*)d_in[4];
    const float* be1   = (const float*)d_in[5];
    const float* Wl1   = (const float*)d_in[6];
    const float* bl1   = (const float*)d_in[7];
    const float* Wr1   = (const float*)d_in[8];
    const float* Wl2   = (const float*)d_in[9];
    const float* bl2   = (const float*)d_in[10];
    const float* Wr2   = (const float*)d_in[11];
    const float* Wskip = (const float*)d_in[12];
    const float* bskip = (const float*)d_in[13];
    const float* g2    = (const float*)d_in[14];
    const float* be2   = (const float*)d_in[15];
    float* out = (float*)d_out;

    char* ws = (char*)d_ws;
    u16*  Z  = (u16*)ws;                                    // 38,400,000 B
    char* zzone = ws + 38400000;
    float* stats = (float*)zzone;                           // 512 f [zeroed]
    int*   icnt  = (int*)(zzone + 2048);                    // N    [zeroed]
    size_t zsz   = 2048 + (size_t)N_NODES * 4;              // 202,048 B
    int*   row_ptr = (int*)(zzone + zsz);                   // N+1
    int*   fillrp  = (int*)(zzone + zsz + 200064);          // N
    int*   bsum    = (int*)(zzone + zsz + 400128);          // 256
    int*   col_idx = (int*)(zzone + zsz + 400128 + 1024);   // E
    float* bnc     = (float*)(zzone + zsz + 400128 + 1024 + (size_t)N_EDGES * 4);
    // bnc: scale1[128] shift1[128] scale2[128] shift2[128] b1eff[128] b2eff[128]
    u16* WfA = (u16*)((char*)bnc + 4096);
    u16* WfB = WfA + 8 * 4096;
    u16* WfC = WfB + 8 * 4096;

    hipMemsetAsync(zzone, 0, zsz, stream);

    const int* srcp = ei;
    const int* dstp = ei + N_EDGES;

    float* scale1 = bnc;
    float* shift1 = bnc + 128;
    float* scale2 = bnc + 256;
    float* shift2 = bnc + 384;
    float* b1eff  = bnc + 512;
    float* b2eff  = bnc + 640;

    // W_in conversion (no scale)
    conv_w<<<16, 256, 0, stream>>>(W_in, nullptr, nullptr, nullptr, nullptr, nullptr,
                                   256, WfA, 8);

    // CSR build
    const int NB = (N_NODES + 255) / 256;   // 196
    edge_count<<<(N_EDGES + 255) / 256, 256, 0, stream>>>(dstp, icnt);
    scan_block<<<NB, 256, 0, stream>>>(icnt, row_ptr, bsum, N_NODES);
    scan_bsum<<<1, 256, 0, stream>>>(bsum, NB);
    scan_add<<<NB, 256, 0, stream>>>(row_ptr, fillrp, bsum, N_NODES);
    edge_fill_part<<<((N_EDGES + FILL_EPB - 1) / FILL_EPB) * 8, 256, 0, stream>>>(
        srcp, dstp, fillrp, col_idx);

    const int GB = (N_NODES + 63) / 64;   // 782

    // layer 0: h_raw = leaky(x @ W_in + b_in) -> Z[:,128:256] bf16, stats1
    gemm_mfma<1, 1, 1, 1><<<GB, 256, 0, stream>>>(
        N_NODES, x, IN_DIM, 256, WfA, b_in, nullptr, Z + 128, ZPITCH, stats);
    bn_params<<<1, 128, 0, stream>>>(stats, g1, be1, scale1, shift1, 1.f / N_NODES);

    // BN1 folded into weights: Wl1,Wr1,Wskip rows scaled by scale1; shift into biases
    conv_w<<<16, 256, 0, stream>>>(Wl1, Wr1, nullptr, scale1, scale1, nullptr,
                                   128, WfB, 8);
    conv_w<<<24, 256, 0, stream>>>(Wl2, Wskip, Wr2, nullptr, scale1, nullptr,
                                   128, WfC, 12);
    bias_fold<<<1, 128, 0, stream>>>(bl1, nullptr, Wl1, Wr1, shift1, b1eff);
    bias_fold<<<1, 128, 0, stream>>>(bl2, bskip, Wskip, nullptr, shift1, b2eff);

    // sage1: h1 = leaky([agg1|h_raw] @ WfB + b1eff) -> Z[:,256:384]
    spmm_mean<<<(N_NODES + 3) / 4, 256, 0, stream>>>(row_ptr, col_idx, Z + 128, Z);
    gemm_mfma<1, 0, 1, 0><<<GB, 256, 0, stream>>>(
        N_NODES, Z, ZPITCH, 256, WfB, b1eff, nullptr, Z + 256, ZPITCH, nullptr);

    // sage2 + skip: out_pre = [agg2|h_raw|h1] @ WfC + b2eff -> d_out fp32, stats2
    spmm_mean<<<(N_NODES + 3) / 4, 256, 0, stream>>>(row_ptr, col_idx, Z + 256, Z);
    gemm_mfma<0, 1, 0, 0><<<GB, 256, 0, stream>>>(
        N_NODES, Z, ZPITCH, 384, WfC, b2eff, nullptr, out, HID, stats + 256);

    // BN2 + row normalize
    bn_params<<<1, 128, 0, stream>>>(stats + 256, g2, be2, scale2, shift2, 1.f / N_NODES);
    bn_rownorm<<<(N_NODES + 3) / 4, 256, 0, stream>>>(out, scale2, shift2);
}

// Round 6
// 276.160 us; speedup vs baseline: 1.1404x; 1.1404x over previous
//
#include <hip/hip_runtime.h>
#include <math.h>

#define N_NODES 50000
#define N_EDGES 800000
#define IN_DIM 256
#define HID 128
#define ZPITCH 384   // [agg:0..128 | h:128..256 | h1:256..384]

typedef unsigned short u16;
typedef u16 u16x8 __attribute__((ext_vector_type(8)));
typedef u16 u16x2 __attribute__((ext_vector_type(2)));
typedef __bf16 bf16x8 __attribute__((ext_vector_type(8)));
typedef float f32x4 __attribute__((ext_vector_type(4)));

union F8 { u16x8 u; bf16x8 h; };

__device__ __forceinline__ u16 f2b(float f) {
    unsigned u = __builtin_bit_cast(unsigned, f);
    u = (u + 0x7FFFu + ((u >> 16) & 1u)) >> 16;   // RNE
    return (u16)u;
}
__device__ __forceinline__ float b2f(u16 h) {
    unsigned u = ((unsigned)h) << 16;
    return __builtin_bit_cast(float, u);
}

// ---------------------------------------------------------------------------
// Unified bf16 MFMA GEMM: C[M,128] = act(A[M,K] @ Wf + bias0 (+bias1)), K=NC*32
// Block = 512 thr (8 waves), BM=128 (1 M-frag/wave).
// Whole fragment-ordered B panel staged to LDS once (linear copy, no swizzle
// needed: frag order IS the read order). ZERO barriers in K-loop. All NC A
// loads issued up-front (static unroll -> registers), so there is exactly one
// global-latency wait per wave; B comes from LDS afterwards.
// ---------------------------------------------------------------------------
template<int A_F32>
__device__ __forceinline__ F8 load_a(const void* base, size_t row, int P, int koff)
{
    F8 r;
    if (A_F32) {
        const float* p = (const float*)base + row * P + koff;
        float4 f0 = *reinterpret_cast<const float4*>(p);
        float4 f1 = *reinterpret_cast<const float4*>(p + 4);
        r.h[0] = (__bf16)f0.x; r.h[1] = (__bf16)f0.y;
        r.h[2] = (__bf16)f0.z; r.h[3] = (__bf16)f0.w;
        r.h[4] = (__bf16)f1.x; r.h[5] = (__bf16)f1.y;
        r.h[6] = (__bf16)f1.z; r.h[7] = (__bf16)f1.w;
    } else {
        r.u = *reinterpret_cast<const u16x8*>((const u16*)base + row * P + koff);
    }
    return r;
}

template<int LEAKY, int STATS, int OUT_BF16, int A_F32, int NC>
__global__ __launch_bounds__(512, 3) void gemm_mfma(
    int M, const void* __restrict__ A, int P,
    const u16* __restrict__ Wf,
    const float* __restrict__ bias0, const float* __restrict__ bias1,
    void* __restrict__ Cout, int CP,
    float* __restrict__ stats)
{
    __shared__ u16 Bs[NC * 4096];   // NC chunks x (32k x 128n) frag-ordered

    const int t   = threadIdx.x;
    const int w   = t >> 6;
    const int l   = t & 63;
    const int l15 = l & 15;
    const int lg  = l >> 4;
    const int rb  = blockIdx.x * 128 + w * 16;

    int r0 = rb + l15;
    size_t r0c = (size_t)(r0 < M ? r0 : M - 1);
    const int ko = lg * 8;

    // ---- A prefetch: all NC chunks, static indices -> registers ----
    F8 a[NC];
#pragma unroll
    for (int c = 0; c < NC; ++c) a[c] = load_a<A_F32>(A, r0c, P, c * 32 + ko);

    // ---- stage B panel to LDS (linear copy of frag-ordered Wf) ----
#pragma unroll
    for (int i = 0; i < NC; ++i) {
        int idx = i * 512 + t;
        reinterpret_cast<u16x8*>(Bs)[idx] = reinterpret_cast<const u16x8*>(Wf)[idx];
    }
    __syncthreads();

    // ---- K-loop: B from LDS, no barriers ----
    f32x4 acc[8];
#pragma unroll
    for (int j = 0; j < 8; ++j) acc[j] = 0.0f;

#pragma unroll
    for (int c = 0; c < NC; ++c) {
#pragma unroll
        for (int j = 0; j < 8; ++j) {
            F8 b;
            b.u = reinterpret_cast<const u16x8*>(Bs)[(c * 8 + j) * 64 + l];
            acc[j] = __builtin_amdgcn_mfma_f32_16x16x32_bf16(a[c].h, b.h, acc[j], 0, 0, 0);
        }
    }

    // ---- epilogue ----
    float bias_j[8];
#pragma unroll
    for (int j = 0; j < 8; ++j) {
        float bb = bias0[16 * j + l15];
        if (bias1) bb += bias1[16 * j + l15];
        bias_j[j] = bb;
    }

    float csum[8], csq[8];
#pragma unroll
    for (int j = 0; j < 8; ++j) { csum[j] = 0.f; csq[j] = 0.f; }

    {
        int rbase = rb + lg * 4;
#pragma unroll
        for (int r = 0; r < 4; ++r) {
            int row = rbase + r;
            bool ok = row < M;
#pragma unroll
            for (int j = 0; j < 8; ++j) {
                float y = acc[j][r] + bias_j[j];
                if (LEAKY) y = (y >= 0.f) ? y : 0.2f * y;
                if (ok) {
                    if (OUT_BF16)
                        ((u16*)Cout)[(size_t)row * CP + 16 * j + l15] = f2b(y);
                    else
                        ((float*)Cout)[(size_t)row * CP + 16 * j + l15] = y;
                    if (STATS) { csum[j] += y; csq[j] += y * y; }
                }
            }
        }
    }

    if (STATS) {
        __shared__ float sred[256];
        if (t < 256) sred[t] = 0.f;
        __syncthreads();
#pragma unroll
        for (int j = 0; j < 8; ++j) {
            float s = csum[j];
            float q = csq[j];
            s += __shfl_xor(s, 16); s += __shfl_xor(s, 32);
            q += __shfl_xor(q, 16); q += __shfl_xor(q, 32);
            if (lg == 0) {
                atomicAdd(&sred[16 * j + l15], s);
                atomicAdd(&sred[128 + 16 * j + l15], q);
            }
        }
        __syncthreads();
        if (t < 256) atomicAdd(&stats[t], sred[t]);
    }
}

// ---------------------------------------------------------------------------
// weight -> fragment-ordered bf16, with optional per-K-row scale (BN fold)
// ---------------------------------------------------------------------------
__global__ __launch_bounds__(256) void conv_w(const float* s0, const float* s1, const float* s2,
                                              const float* sc0, const float* sc1, const float* sc2,
                                              int rows_each, u16* __restrict__ dst, int nchunks)
{
    int tid = blockIdx.x * 256 + threadIdx.x;
    if (tid >= nchunks * 512) return;
    int c   = tid >> 9;
    int j   = (tid >> 6) & 7;
    int l   = tid & 63;
    int l15 = l & 15, lg = l >> 4;

    int srow0 = c * 32;
    int si    = srow0 / rows_each;
    const float* S  = (si == 0) ? s0 : (si == 1) ? s1 : s2;
    const float* SC = (si == 0) ? sc0 : (si == 1) ? sc1 : sc2;
    int rbase = srow0 - si * rows_each + lg * 8;
    int col   = 16 * j + l15;

    u16x8 o;
#pragma unroll
    for (int i = 0; i < 8; ++i) {
        float v = S[(size_t)(rbase + i) * HID + col];
        if (SC) v *= SC[rbase + i];
        o[i] = f2b(v);
    }
    reinterpret_cast<u16x8*>(dst)[tid] = o;
}

// bias fold: outb[j] = b0[j] (+b1[j]) + sum_i sh[i]*(W0[i][j] (+W1[i][j]))
__global__ void bias_fold(const float* __restrict__ b0, const float* __restrict__ b1,
                          const float* __restrict__ W0, const float* __restrict__ W1,
                          const float* __restrict__ sh, float* __restrict__ outb)
{
    int j = threadIdx.x;   // 128
    float acc = b0[j] + (b1 ? b1[j] : 0.f);
    for (int i = 0; i < HID; ++i) {
        float w = W0[(size_t)i * HID + j] + (W1 ? W1[(size_t)i * HID + j] : 0.f);
        acc = fmaf(sh[i], w, acc);
    }
    outb[j] = acc;
}

// ---------------------------------------------------------------------------
// BatchNorm params
// ---------------------------------------------------------------------------
__global__ void bn_params(const float* __restrict__ stats,
                          const float* __restrict__ gamma,
                          const float* __restrict__ beta,
                          float* __restrict__ scale,
                          float* __restrict__ shift, float invn)
{
    int j = threadIdx.x;
    float mean = stats[j] * invn;
    float var  = stats[128 + j] * invn - mean * mean;
    var = fmaxf(var, 0.f);
    float sc = gamma[j] / sqrtf(var + 1e-5f);
    scale[j] = sc;
    shift[j] = beta[j] - mean * sc;
}

// ---------------------------------------------------------------------------
// CSR build
// ---------------------------------------------------------------------------
__global__ __launch_bounds__(256) void edge_count(const int* __restrict__ dst, int* __restrict__ cnt)
{
    int e = blockIdx.x * 256 + threadIdx.x;
    if (e < N_EDGES) atomicAdd(&cnt[dst[e]], 1);
}

__global__ __launch_bounds__(256) void scan_block(const int* __restrict__ cnt,
                                                  int* __restrict__ excl,
                                                  int* __restrict__ bsum, int n)
{
    __shared__ int sh[256];
    int t = threadIdx.x;
    int i = blockIdx.x * 256 + t;
    int v = (i < n) ? cnt[i] : 0;
    sh[t] = v;
    __syncthreads();
#pragma unroll
    for (int off = 1; off < 256; off <<= 1) {
        int x = (t >= off) ? sh[t - off] : 0;
        __syncthreads();
        sh[t] += x;
        __syncthreads();
    }
    if (i < n) excl[i] = sh[t] - v;
    if (t == 255) bsum[blockIdx.x] = sh[255];
}

__global__ __launch_bounds__(256) void scan_bsum(int* __restrict__ bsum, int nb)
{
    __shared__ int sh[256];
    int t = threadIdx.x;
    int v = (t < nb) ? bsum[t] : 0;
    sh[t] = v;
    __syncthreads();
#pragma unroll
    for (int off = 1; off < 256; off <<= 1) {
        int x = (t >= off) ? sh[t - off] : 0;
        __syncthreads();
        sh[t] += x;
        __syncthreads();
    }
    if (t < nb) bsum[t] = sh[t] - v;   // exclusive
}

__global__ __launch_bounds__(256) void scan_add(int* __restrict__ row_ptr,
                                                int* __restrict__ fillrp,
                                                const int* __restrict__ bsum, int n)
{
    int i = blockIdx.x * 256 + threadIdx.x;
    if (i < n) {
        int v = row_ptr[i] + bsum[i >> 8];
        row_ptr[i] = v;
        fillrp[i]  = v;
    }
    if (i == 0) row_ptr[n] = N_EDGES;
}

// XCD-partitioned CSR fill (keeps col_idx line writes XCD-local)
#define FILL_EPB 4096
__global__ __launch_bounds__(256) void edge_fill_part(const int* __restrict__ src,
                                                      const int* __restrict__ dst,
                                                      int* __restrict__ fillrp,
                                                      int* __restrict__ col_idx)
{
    const int range = blockIdx.x & 7;
    const int base  = (blockIdx.x >> 3) * FILL_EPB;
    const int lo = range * 6250, hi = lo + 6250;
#pragma unroll
    for (int k = 0; k < FILL_EPB / 256; ++k) {
        int e = base + k * 256 + threadIdx.x;
        if (e < N_EDGES) {
            int d = dst[e];
            if (d >= lo && d < hi) {
                int pos = atomicAdd(&fillrp[d], 1);
                col_idx[pos] = src[e];
            }
        }
    }
}

// ---------------------------------------------------------------------------
// SpMM mean over bf16 rows in Z. One wave per node, ushort2 per lane.
// ---------------------------------------------------------------------------
__global__ __launch_bounds__(256) void spmm_mean(const int* __restrict__ row_ptr,
                                                 const int* __restrict__ col_idx,
                                                 const u16* __restrict__ Z_in,
                                                 u16* __restrict__ Z_out)
{
    int node = blockIdx.x * 4 + (threadIdx.x >> 6);
    if (node >= N_NODES) return;
    int lane = threadIdx.x & 63;
    int beg = row_ptr[node];
    int end = row_ptr[node + 1];

    float sx = 0.f, sy = 0.f;
    int e = beg;
    for (; e + 4 <= end; e += 4) {
        int c0 = col_idx[e], c1 = col_idx[e + 1], c2 = col_idx[e + 2], c3 = col_idx[e + 3];
        u16x2 v0 = *reinterpret_cast<const u16x2*>(Z_in + (size_t)c0 * ZPITCH + lane * 2);
        u16x2 v1 = *reinterpret_cast<const u16x2*>(Z_in + (size_t)c1 * ZPITCH + lane * 2);
        u16x2 v2 = *reinterpret_cast<const u16x2*>(Z_in + (size_t)c2 * ZPITCH + lane * 2);
        u16x2 v3 = *reinterpret_cast<const u16x2*>(Z_in + (size_t)c3 * ZPITCH + lane * 2);
        sx += (b2f(v0[0]) + b2f(v1[0])) + (b2f(v2[0]) + b2f(v3[0]));
        sy += (b2f(v0[1]) + b2f(v1[1])) + (b2f(v2[1]) + b2f(v3[1]));
    }
    for (; e < end; ++e) {
        int c = col_idx[e];
        u16x2 v = *reinterpret_cast<const u16x2*>(Z_in + (size_t)c * ZPITCH + lane * 2);
        sx += b2f(v[0]); sy += b2f(v[1]);
    }
    float inv = 1.f / fmaxf((float)(end - beg), 1.f);
    u16x2 r; r[0] = f2b(sx * inv); r[1] = f2b(sy * inv);
    *reinterpret_cast<u16x2*>(Z_out + (size_t)node * ZPITCH + lane * 2) = r;
}

// ---------------------------------------------------------------------------
// Final: BN2 apply + L2 row-normalize, in place on d_out (fp32). One wave/row.
// ---------------------------------------------------------------------------
__global__ __launch_bounds__(256) void bn_rownorm(float* __restrict__ out,
                                                  const float* __restrict__ scale,
                                                  const float* __restrict__ shift)
{
    int row = blockIdx.x * 4 + (threadIdx.x >> 6);
    if (row >= N_NODES) return;
    int lane = threadIdx.x & 63;
    float2 v  = *reinterpret_cast<const float2*>(&out[(size_t)row * HID + lane * 2]);
    float2 sc = *reinterpret_cast<const float2*>(&scale[lane * 2]);
    float2 sh = *reinterpret_cast<const float2*>(&shift[lane * 2]);
    float y0 = v.x * sc.x + sh.x;
    float y1 = v.y * sc.y + sh.y;
    float ss = y0 * y0 + y1 * y1;
#pragma unroll
    for (int m = 1; m < 64; m <<= 1) ss += __shfl_xor(ss, m);
    float inv = 1.f / fmaxf(sqrtf(ss), 1e-12f);
    float2 r = {y0 * inv, y1 * inv};
    *reinterpret_cast<float2*>(&out[(size_t)row * HID + lane * 2]) = r;
}

// ---------------------------------------------------------------------------
extern "C" void kernel_launch(void* const* d_in, const int* in_sizes, int n_in,
                              void* d_out, int out_size, void* d_ws, size_t ws_size,
                              hipStream_t stream)
{
    const float* x     = (const float*)d_in[0];
    const int*   ei    = (const int*)d_in[1];
    const float* W_in  = (const float*)d_in[2];
    const float* b_in  = (const float*)d_in[3];
    const float* g1    = (const float*)d_in[4];
    const float* be1   = (const float*)d_in[5];
    const float* Wl1   = (const float*)d_in[6];
    const float* bl1   = (const float*)d_in[7];
    const float* Wr1   = (const float*)d_in[8];
    const float* Wl2   = (const float*)d_in[9];
    const float* bl2   = (const float*)d_in[10];
    const float* Wr2   = (const float*)d_in[11];
    const float* Wskip = (const float*)d_in[12];
    const float* bskip = (const float*)d_in[13];
    const float* g2    = (const float*)d_in[14];
    const float* be2   = (const float*)d_in[15];
    float* out = (float*)d_out;

    char* ws = (char*)d_ws;
    u16*  Z  = (u16*)ws;                                    // 38,400,000 B
    char* zzone = ws + 38400000;
    float* stats = (float*)zzone;                           // 512 f [zeroed]
    int*   icnt  = (int*)(zzone + 2048);                    // N    [zeroed]
    size_t zsz   = 2048 + (size_t)N_NODES * 4;              // 202,048 B
    int*   row_ptr = (int*)(zzone + zsz);                   // N+1
    int*   fillrp  = (int*)(zzone + zsz + 200064);          // N
    int*   bsum    = (int*)(zzone + zsz + 400128);          // 256
    int*   col_idx = (int*)(zzone + zsz + 400128 + 1024);   // E
    float* bnc     = (float*)(zzone + zsz + 400128 + 1024 + (size_t)N_EDGES * 4);
    // bnc: scale1[128] shift1[128] scale2[128] shift2[128] b1eff[128] b2eff[128]
    u16* WfA = (u16*)((char*)bnc + 4096);
    u16* WfB = WfA + 8 * 4096;
    u16* WfC = WfB + 8 * 4096;

    hipMemsetAsync(zzone, 0, zsz, stream);

    const int* srcp = ei;
    const int* dstp = ei + N_EDGES;

    float* scale1 = bnc;
    float* shift1 = bnc + 128;
    float* scale2 = bnc + 256;
    float* shift2 = bnc + 384;
    float* b1eff  = bnc + 512;
    float* b2eff  = bnc + 640;

    // W_in conversion (no scale)
    conv_w<<<16, 256, 0, stream>>>(W_in, nullptr, nullptr, nullptr, nullptr, nullptr,
                                   256, WfA, 8);

    // CSR build
    const int NB = (N_NODES + 255) / 256;   // 196
    edge_count<<<(N_EDGES + 255) / 256, 256, 0, stream>>>(dstp, icnt);
    scan_block<<<NB, 256, 0, stream>>>(icnt, row_ptr, bsum, N_NODES);
    scan_bsum<<<1, 256, 0, stream>>>(bsum, NB);
    scan_add<<<NB, 256, 0, stream>>>(row_ptr, fillrp, bsum, N_NODES);
    edge_fill_part<<<((N_EDGES + FILL_EPB - 1) / FILL_EPB) * 8, 256, 0, stream>>>(
        srcp, dstp, fillrp, col_idx);

    const int GB = (N_NODES + 127) / 128;   // 391

    // layer 0: h_raw = leaky(x @ W_in + b_in) -> Z[:,128:256] bf16, stats1
    gemm_mfma<1, 1, 1, 1, 8><<<GB, 512, 0, stream>>>(
        N_NODES, x, IN_DIM, WfA, b_in, nullptr, Z + 128, ZPITCH, stats);
    bn_params<<<1, 128, 0, stream>>>(stats, g1, be1, scale1, shift1, 1.f / N_NODES);

    // BN1 folded into weights: Wl1,Wr1,Wskip rows scaled by scale1; shift into biases
    conv_w<<<16, 256, 0, stream>>>(Wl1, Wr1, nullptr, scale1, scale1, nullptr,
                                   128, WfB, 8);
    conv_w<<<24, 256, 0, stream>>>(Wl2, Wskip, Wr2, nullptr, scale1, nullptr,
                                   128, WfC, 12);
    bias_fold<<<1, 128, 0, stream>>>(bl1, nullptr, Wl1, Wr1, shift1, b1eff);
    bias_fold<<<1, 128, 0, stream>>>(bl2, bskip, Wskip, nullptr, shift1, b2eff);

    // sage1: h1 = leaky([agg1|h_raw] @ WfB + b1eff) -> Z[:,256:384]
    spmm_mean<<<(N_NODES + 3) / 4, 256, 0, stream>>>(row_ptr, col_idx, Z + 128, Z);
    gemm_mfma<1, 0, 1, 0, 8><<<GB, 512, 0, stream>>>(
        N_NODES, Z, ZPITCH, WfB, b1eff, nullptr, Z + 256, ZPITCH, nullptr);

    // sage2 + skip: out_pre = [agg2|h_raw|h1] @ WfC + b2eff -> d_out fp32, stats2
    spmm_mean<<<(N_NODES + 3) / 4, 256, 0, stream>>>(row_ptr, col_idx, Z + 256, Z);
    gemm_mfma<0, 1, 0, 0, 12><<<GB, 512, 0, stream>>>(
        N_NODES, Z, ZPITCH, WfC, b2eff, nullptr, out, HID, stats + 256);

    // BN2 + row normalize
    bn_params<<<1, 128, 0, stream>>>(stats + 256, g2, be2, scale2, shift2, 1.f / N_NODES);
    bn_rownorm<<<(N_NODES + 3) / 4, 256, 0, stream>>>(out, scale2, shift2);
}

// Round 7
// 268.569 us; speedup vs baseline: 1.1726x; 1.0283x over previous
//
#include <hip/hip_runtime.h>
#include <math.h>

#define N_NODES 50000
#define N_EDGES 800000
#define IN_DIM 256
#define HID 128
#define ZPITCH 384   // [agg:0..128 | h:128..256 | h1:256..384]

typedef unsigned short u16;
typedef u16 u16x8 __attribute__((ext_vector_type(8)));
typedef u16 u16x2 __attribute__((ext_vector_type(2)));
typedef __bf16 bf16x8 __attribute__((ext_vector_type(8)));
typedef float f32x4 __attribute__((ext_vector_type(4)));

#define AS1 __attribute__((address_space(1)))
#define AS3 __attribute__((address_space(3)))

union F8 { u16x8 u; bf16x8 h; };

__device__ __forceinline__ u16 f2b(float f) {
    unsigned u = __builtin_bit_cast(unsigned, f);
    u = (u + 0x7FFFu + ((u >> 16) & 1u)) >> 16;   // RNE
    return (u16)u;
}
__device__ __forceinline__ float b2f(u16 h) {
    unsigned u = ((unsigned)h) << 16;
    return __builtin_bit_cast(float, u);
}

// ---------------------------------------------------------------------------
// Raw A-chunk holders: load issues the global load; to_frag converts at USE
// site so the vmcnt wait lands in the consuming iteration, not the issue site.
// ---------------------------------------------------------------------------
template<int A_F32> struct ARaw;
template<> struct ARaw<0> { u16x8 v; };
template<> struct ARaw<1> { float4 f0, f1; };

template<int A_F32>
__device__ __forceinline__ ARaw<A_F32> load_raw(const void* base, size_t row, int P, int koff);
template<>
__device__ __forceinline__ ARaw<0> load_raw<0>(const void* base, size_t row, int P, int koff) {
    ARaw<0> r;
    r.v = *reinterpret_cast<const u16x8*>((const u16*)base + row * P + koff);
    return r;
}
template<>
__device__ __forceinline__ ARaw<1> load_raw<1>(const void* base, size_t row, int P, int koff) {
    ARaw<1> r;
    const float* p = (const float*)base + row * P + koff;
    r.f0 = *reinterpret_cast<const float4*>(p);
    r.f1 = *reinterpret_cast<const float4*>(p + 4);
    return r;
}

template<int A_F32>
__device__ __forceinline__ F8 to_frag(const ARaw<A_F32>& r);
template<>
__device__ __forceinline__ F8 to_frag<0>(const ARaw<0>& r) { F8 f; f.u = r.v; return f; }
template<>
__device__ __forceinline__ F8 to_frag<1>(const ARaw<1>& r) {
    F8 f;
    f.h[0] = (__bf16)r.f0.x; f.h[1] = (__bf16)r.f0.y;
    f.h[2] = (__bf16)r.f0.z; f.h[3] = (__bf16)r.f0.w;
    f.h[4] = (__bf16)r.f1.x; f.h[5] = (__bf16)r.f1.y;
    f.h[6] = (__bf16)r.f1.z; f.h[7] = (__bf16)r.f1.w;
    return f;
}

// ---------------------------------------------------------------------------
// Unified bf16 MFMA GEMM: C[M,128] = act(A[M,K] @ Wf + bias), K = NC*32.
// Block = 512 thr (8 waves), BM=256: wave w owns rows [bid*256+w*32, +32)
// as 2 M-frags. Grid = ceil(M/256) = 196 <= 256 CUs -> single dispatch round.
// B panel (frag-ordered) staged to LDS via global_load_lds (linear layout ==
// read order). K-loop: explicit register double-buffer for B (nb prefetch),
// rolling depth-4 A prefetch in raw form. Zero barriers in K-loop.
// ---------------------------------------------------------------------------
template<int LEAKY, int STATS, int OUT_BF16, int A_F32, int NC>
__global__ __launch_bounds__(512, 2) void gemm_mfma(
    int M, const void* __restrict__ A, int P,
    const u16* __restrict__ Wf,
    const float* __restrict__ bias0,
    void* __restrict__ Cout, int CP,
    float* __restrict__ stats)
{
    __shared__ u16 Bs[NC * 4096];

    const int t   = threadIdx.x;
    const int w   = t >> 6;
    const int l   = t & 63;
    const int l15 = l & 15;
    const int lg  = l >> 4;
    const int rb  = blockIdx.x * 256 + w * 32;

    int r0 = rb + l15;
    int r1 = r0 + 16;
    size_t r0c = (size_t)(r0 < M ? r0 : M - 1);
    size_t r1c = (size_t)(r1 < M ? r1 : M - 1);
    const int ko = lg * 8;

    // ---- B panel -> LDS, async, no VGPR roundtrip ----
#pragma unroll
    for (int i = 0; i < NC; ++i) {
        int idx = i * 512 + t;
        __builtin_amdgcn_global_load_lds(
            (const AS1 void*)(Wf + (size_t)idx * 8),
            (AS3 void*)(Bs + (size_t)idx * 8), 16, 0, 0);
    }

    // ---- rolling A prefetch (depth 4), raw form ----
    constexpr int D = (NC < 4) ? NC : 4;
    ARaw<A_F32> a0[NC], a1[NC];
#pragma unroll
    for (int c = 0; c < D; ++c) {
        a0[c] = load_raw<A_F32>(A, r0c, P, c * 32 + ko);
        a1[c] = load_raw<A_F32>(A, r1c, P, c * 32 + ko);
    }

    __syncthreads();   // drains global_load_lds (and issued A loads)

    f32x4 acc[2][8];
#pragma unroll
    for (int m = 0; m < 2; ++m)
#pragma unroll
        for (int j = 0; j < 8; ++j) acc[m][j] = 0.0f;

    F8 b[8], nb[8];
#pragma unroll
    for (int j = 0; j < 8; ++j)
        b[j].u = *reinterpret_cast<const u16x8*>(Bs + (size_t)(j * 64 + l) * 8);

#pragma unroll
    for (int c = 0; c < NC; ++c) {
        // refill A ring
        if (c + D < NC) {
            a0[c + D] = load_raw<A_F32>(A, r0c, P, (c + D) * 32 + ko);
            a1[c + D] = load_raw<A_F32>(A, r1c, P, (c + D) * 32 + ko);
        }
        // prefetch next B chunk from LDS
        if (c + 1 < NC) {
#pragma unroll
            for (int j = 0; j < 8; ++j)
                nb[j].u = *reinterpret_cast<const u16x8*>(
                    Bs + (size_t)(((c + 1) * 8 + j) * 64 + l) * 8);
        }
        // compute on current b / a[c]
        F8 fa0 = to_frag<A_F32>(a0[c]);
        F8 fa1 = to_frag<A_F32>(a1[c]);
#pragma unroll
        for (int j = 0; j < 8; ++j) {
            acc[0][j] = __builtin_amdgcn_mfma_f32_16x16x32_bf16(fa0.h, b[j].h, acc[0][j], 0, 0, 0);
            acc[1][j] = __builtin_amdgcn_mfma_f32_16x16x32_bf16(fa1.h, b[j].h, acc[1][j], 0, 0, 0);
        }
#pragma unroll
        for (int j = 0; j < 8; ++j) b[j] = nb[j];
    }

    // ---- epilogue ----
    float bias_j[8];
#pragma unroll
    for (int j = 0; j < 8; ++j) bias_j[j] = bias0[16 * j + l15];

    float csum[8], csq[8];
#pragma unroll
    for (int j = 0; j < 8; ++j) { csum[j] = 0.f; csq[j] = 0.f; }

#pragma unroll
    for (int m = 0; m < 2; ++m) {
        int rbase = rb + m * 16 + lg * 4;
#pragma unroll
        for (int r = 0; r < 4; ++r) {
            int row = rbase + r;
            bool ok = row < M;
#pragma unroll
            for (int j = 0; j < 8; ++j) {
                float y = acc[m][j][r] + bias_j[j];
                if (LEAKY) y = (y >= 0.f) ? y : 0.2f * y;
                if (ok) {
                    if (OUT_BF16)
                        ((u16*)Cout)[(size_t)row * CP + 16 * j + l15] = f2b(y);
                    else
                        ((float*)Cout)[(size_t)row * CP + 16 * j + l15] = y;
                    if (STATS) { csum[j] += y; csq[j] += y * y; }
                }
            }
        }
    }

    if (STATS) {
        __shared__ float sred[256];
        if (t < 256) sred[t] = 0.f;
        __syncthreads();
#pragma unroll
        for (int j = 0; j < 8; ++j) {
            float s = csum[j];
            float q = csq[j];
            s += __shfl_xor(s, 16); s += __shfl_xor(s, 32);
            q += __shfl_xor(q, 16); q += __shfl_xor(q, 32);
            if (lg == 0) {
                atomicAdd(&sred[16 * j + l15], s);
                atomicAdd(&sred[128 + 16 * j + l15], q);
            }
        }
        __syncthreads();
        if (t < 256) atomicAdd(&stats[t], sred[t]);
    }
}

// ---------------------------------------------------------------------------
// weight -> fragment-ordered bf16, with optional per-K-row scale (BN fold)
// ---------------------------------------------------------------------------
__global__ __launch_bounds__(256) void conv_w(const float* s0, const float* s1, const float* s2,
                                              const float* sc0, const float* sc1, const float* sc2,
                                              int rows_each, u16* __restrict__ dst, int nchunks)
{
    int tid = blockIdx.x * 256 + threadIdx.x;
    if (tid >= nchunks * 512) return;
    int c   = tid >> 9;
    int j   = (tid >> 6) & 7;
    int l   = tid & 63;
    int l15 = l & 15, lg = l >> 4;

    int srow0 = c * 32;
    int si    = srow0 / rows_each;
    const float* S  = (si == 0) ? s0 : (si == 1) ? s1 : s2;
    const float* SC = (si == 0) ? sc0 : (si == 1) ? sc1 : sc2;
    int rbase = srow0 - si * rows_each + lg * 8;
    int col   = 16 * j + l15;

    u16x8 o;
#pragma unroll
    for (int i = 0; i < 8; ++i) {
        float v = S[(size_t)(rbase + i) * HID + col];
        if (SC) v *= SC[rbase + i];
        o[i] = f2b(v);
    }
    reinterpret_cast<u16x8*>(dst)[tid] = o;
}

// bias fold: outb[j] = b0[j] (+b1[j]) + sum_i sh[i]*(W0[i][j] (+W1[i][j]))
__global__ void bias_fold(const float* __restrict__ b0, const float* __restrict__ b1,
                          const float* __restrict__ W0, const float* __restrict__ W1,
                          const float* __restrict__ sh, float* __restrict__ outb)
{
    int j = threadIdx.x;   // 128
    float acc = b0[j] + (b1 ? b1[j] : 0.f);
    for (int i = 0; i < HID; ++i) {
        float w = W0[(size_t)i * HID + j] + (W1 ? W1[(size_t)i * HID + j] : 0.f);
        acc = fmaf(sh[i], w, acc);
    }
    outb[j] = acc;
}

// ---------------------------------------------------------------------------
// BatchNorm params
// ---------------------------------------------------------------------------
__global__ void bn_params(const float* __restrict__ stats,
                          const float* __restrict__ gamma,
                          const float* __restrict__ beta,
                          float* __restrict__ scale,
                          float* __restrict__ shift, float invn)
{
    int j = threadIdx.x;
    float mean = stats[j] * invn;
    float var  = stats[128 + j] * invn - mean * mean;
    var = fmaxf(var, 0.f);
    float sc = gamma[j] / sqrtf(var + 1e-5f);
    scale[j] = sc;
    shift[j] = beta[j] - mean * sc;
}

// ---------------------------------------------------------------------------
// CSR build
// ---------------------------------------------------------------------------
__global__ __launch_bounds__(256) void edge_count(const int* __restrict__ dst, int* __restrict__ cnt)
{
    int e = blockIdx.x * 256 + threadIdx.x;
    if (e < N_EDGES) atomicAdd(&cnt[dst[e]], 1);
}

__global__ __launch_bounds__(256) void scan_block(const int* __restrict__ cnt,
                                                  int* __restrict__ excl,
                                                  int* __restrict__ bsum, int n)
{
    __shared__ int sh[256];
    int t = threadIdx.x;
    int i = blockIdx.x * 256 + t;
    int v = (i < n) ? cnt[i] : 0;
    sh[t] = v;
    __syncthreads();
#pragma unroll
    for (int off = 1; off < 256; off <<= 1) {
        int x = (t >= off) ? sh[t - off] : 0;
        __syncthreads();
        sh[t] += x;
        __syncthreads();
    }
    if (i < n) excl[i] = sh[t] - v;
    if (t == 255) bsum[blockIdx.x] = sh[255];
}

__global__ __launch_bounds__(256) void scan_bsum(int* __restrict__ bsum, int nb)
{
    __shared__ int sh[256];
    int t = threadIdx.x;
    int v = (t < nb) ? bsum[t] : 0;
    sh[t] = v;
    __syncthreads();
#pragma unroll
    for (int off = 1; off < 256; off <<= 1) {
        int x = (t >= off) ? sh[t - off] : 0;
        __syncthreads();
        sh[t] += x;
        __syncthreads();
    }
    if (t < nb) bsum[t] = sh[t] - v;   // exclusive
}

__global__ __launch_bounds__(256) void scan_add(int* __restrict__ row_ptr,
                                                int* __restrict__ fillrp,
                                                const int* __restrict__ bsum, int n)
{
    int i = blockIdx.x * 256 + threadIdx.x;
    if (i < n) {
        int v = row_ptr[i] + bsum[i >> 8];
        row_ptr[i] = v;
        fillrp[i]  = v;
    }
    if (i == 0) row_ptr[n] = N_EDGES;
}

// XCD-partitioned CSR fill (keeps col_idx line writes XCD-local)
#define FILL_EPB 4096
__global__ __launch_bounds__(256) void edge_fill_part(const int* __restrict__ src,
                                                      const int* __restrict__ dst,
                                                      int* __restrict__ fillrp,
                                                      int* __restrict__ col_idx)
{
    const int range = blockIdx.x & 7;
    const int base  = (blockIdx.x >> 3) * FILL_EPB;
    const int lo = range * 6250, hi = lo + 6250;
#pragma unroll
    for (int k = 0; k < FILL_EPB / 256; ++k) {
        int e = base + k * 256 + threadIdx.x;
        if (e < N_EDGES) {
            int d = dst[e];
            if (d >= lo && d < hi) {
                int pos = atomicAdd(&fillrp[d], 1);
                col_idx[pos] = src[e];
            }
        }
    }
}

// ---------------------------------------------------------------------------
// SpMM mean over bf16 rows in Z. One wave per node, ushort2 per lane.
// ---------------------------------------------------------------------------
__global__ __launch_bounds__(256) void spmm_mean(const int* __restrict__ row_ptr,
                                                 const int* __restrict__ col_idx,
                                                 const u16* __restrict__ Z_in,
                                                 u16* __restrict__ Z_out)
{
    int node = blockIdx.x * 4 + (threadIdx.x >> 6);
    if (node >= N_NODES) return;
    int lane = threadIdx.x & 63;
    int beg = row_ptr[node];
    int end = row_ptr[node + 1];

    float sx = 0.f, sy = 0.f;
    int e = beg;
    for (; e + 4 <= end; e += 4) {
        int c0 = col_idx[e], c1 = col_idx[e + 1], c2 = col_idx[e + 2], c3 = col_idx[e + 3];
        u16x2 v0 = *reinterpret_cast<const u16x2*>(Z_in + (size_t)c0 * ZPITCH + lane * 2);
        u16x2 v1 = *reinterpret_cast<const u16x2*>(Z_in + (size_t)c1 * ZPITCH + lane * 2);
        u16x2 v2 = *reinterpret_cast<const u16x2*>(Z_in + (size_t)c2 * ZPITCH + lane * 2);
        u16x2 v3 = *reinterpret_cast<const u16x2*>(Z_in + (size_t)c3 * ZPITCH + lane * 2);
        sx += (b2f(v0[0]) + b2f(v1[0])) + (b2f(v2[0]) + b2f(v3[0]));
        sy += (b2f(v0[1]) + b2f(v1[1])) + (b2f(v2[1]) + b2f(v3[1]));
    }
    for (; e < end; ++e) {
        int c = col_idx[e];
        u16x2 v = *reinterpret_cast<const u16x2*>(Z_in + (size_t)c * ZPITCH + lane * 2);
        sx += b2f(v[0]); sy += b2f(v[1]);
    }
    float inv = 1.f / fmaxf((float)(end - beg), 1.f);
    u16x2 r; r[0] = f2b(sx * inv); r[1] = f2b(sy * inv);
    *reinterpret_cast<u16x2*>(Z_out + (size_t)node * ZPITCH + lane * 2) = r;
}

// ---------------------------------------------------------------------------
// Final: BN2 apply + L2 row-normalize, in place on d_out (fp32). One wave/row.
// ---------------------------------------------------------------------------
__global__ __launch_bounds__(256) void bn_rownorm(float* __restrict__ out,
                                                  const float* __restrict__ scale,
                                                  const float* __restrict__ shift)
{
    int row = blockIdx.x * 4 + (threadIdx.x >> 6);
    if (row >= N_NODES) return;
    int lane = threadIdx.x & 63;
    float2 v  = *reinterpret_cast<const float2*>(&out[(size_t)row * HID + lane * 2]);
    float2 sc = *reinterpret_cast<const float2*>(&scale[lane * 2]);
    float2 sh = *reinterpret_cast<const float2*>(&shift[lane * 2]);
    float y0 = v.x * sc.x + sh.x;
    float y1 = v.y * sc.y + sh.y;
    float ss = y0 * y0 + y1 * y1;
#pragma unroll
    for (int m = 1; m < 64; m <<= 1) ss += __shfl_xor(ss, m);
    float inv = 1.f / fmaxf(sqrtf(ss), 1e-12f);
    float2 r = {y0 * inv, y1 * inv};
    *reinterpret_cast<float2*>(&out[(size_t)row * HID + lane * 2]) = r;
}

// ---------------------------------------------------------------------------
extern "C" void kernel_launch(void* const* d_in, const int* in_sizes, int n_in,
                              void* d_out, int out_size, void* d_ws, size_t ws_size,
                              hipStream_t stream)
{
    const float* x     = (const float*)d_in[0];
    const int*   ei    = (const int*)d_in[1];
    const float* W_in  = (const float*)d_in[2];
    const float* b_in  = (const float*)d_in[3];
    const float* g1    = (const float*)d_in[4];
    const float* be1   = (const float*)d_in[5];
    const float* Wl1   = (const float*)d_in[6];
    const float* bl1   = (const float*)d_in[7];
    const float* Wr1   = (const float*)d_in[8];
    const float* Wl2   = (const float*)d_in[9];
    const float* bl2   = (const float*)d_in[10];
    const float* Wr2   = (const float*)d_in[11];
    const float* Wskip = (const float*)d_in[12];
    const float* bskip = (const float*)d_in[13];
    const float* g2    = (const float*)d_in[14];
    const float* be2   = (const float*)d_in[15];
    float* out = (float*)d_out;

    char* ws = (char*)d_ws;
    u16*  Z  = (u16*)ws;                                    // 38,400,000 B
    char* zzone = ws + 38400000;
    float* stats = (float*)zzone;                           // 512 f [zeroed]
    int*   icnt  = (int*)(zzone + 2048);                    // N    [zeroed]
    size_t zsz   = 2048 + (size_t)N_NODES * 4;              // 202,048 B
    int*   row_ptr = (int*)(zzone + zsz);                   // N+1
    int*   fillrp  = (int*)(zzone + zsz + 200064);          // N
    int*   bsum    = (int*)(zzone + zsz + 400128);          // 256
    int*   col_idx = (int*)(zzone + zsz + 400128 + 1024);   // E
    float* bnc     = (float*)(zzone + zsz + 400128 + 1024 + (size_t)N_EDGES * 4);
    // bnc: scale1[128] shift1[128] scale2[128] shift2[128] b1eff[128] b2eff[128]
    u16* WfA = (u16*)((char*)bnc + 4096);
    u16* WfB = WfA + 8 * 4096;
    u16* WfC = WfB + 8 * 4096;

    hipMemsetAsync(zzone, 0, zsz, stream);

    const int* srcp = ei;
    const int* dstp = ei + N_EDGES;

    float* scale1 = bnc;
    float* shift1 = bnc + 128;
    float* scale2 = bnc + 256;
    float* shift2 = bnc + 384;
    float* b1eff  = bnc + 512;
    float* b2eff  = bnc + 640;

    // W_in conversion (no scale)
    conv_w<<<16, 256, 0, stream>>>(W_in, nullptr, nullptr, nullptr, nullptr, nullptr,
                                   256, WfA, 8);

    // CSR build
    const int NB = (N_NODES + 255) / 256;   // 196
    edge_count<<<(N_EDGES + 255) / 256, 256, 0, stream>>>(dstp, icnt);
    scan_block<<<NB, 256, 0, stream>>>(icnt, row_ptr, bsum, N_NODES);
    scan_bsum<<<1, 256, 0, stream>>>(bsum, NB);
    scan_add<<<NB, 256, 0, stream>>>(row_ptr, fillrp, bsum, N_NODES);
    edge_fill_part<<<((N_EDGES + FILL_EPB - 1) / FILL_EPB) * 8, 256, 0, stream>>>(
        srcp, dstp, fillrp, col_idx);

    const int GB = (N_NODES + 255) / 256;   // 196 blocks (BM=256) -> 1 round

    // layer 0: h_raw = leaky(x @ W_in + b_in) -> Z[:,128:256] bf16, stats1
    gemm_mfma<1, 1, 1, 1, 8><<<GB, 512, 0, stream>>>(
        N_NODES, x, IN_DIM, WfA, b_in, Z + 128, ZPITCH, stats);
    bn_params<<<1, 128, 0, stream>>>(stats, g1, be1, scale1, shift1, 1.f / N_NODES);

    // BN1 folded into weights: Wl1,Wr1,Wskip rows scaled by scale1; shift into biases
    conv_w<<<16, 256, 0, stream>>>(Wl1, Wr1, nullptr, scale1, scale1, nullptr,
                                   128, WfB, 8);
    conv_w<<<24, 256, 0, stream>>>(Wl2, Wskip, Wr2, nullptr, scale1, nullptr,
                                   128, WfC, 12);
    bias_fold<<<1, 128, 0, stream>>>(bl1, nullptr, Wl1, Wr1, shift1, b1eff);
    bias_fold<<<1, 128, 0, stream>>>(bl2, bskip, Wskip, nullptr, shift1, b2eff);

    // sage1: h1 = leaky([agg1|h_raw] @ WfB + b1eff) -> Z[:,256:384]
    spmm_mean<<<(N_NODES + 3) / 4, 256, 0, stream>>>(row_ptr, col_idx, Z + 128, Z);
    gemm_mfma<1, 0, 1, 0, 8><<<GB, 512, 0, stream>>>(
        N_NODES, Z, ZPITCH, WfB, b1eff, Z + 256, ZPITCH, nullptr);

    // sage2 + skip: out_pre = [agg2|h_raw|h1] @ WfC + b2eff -> d_out fp32, stats2
    spmm_mean<<<(N_NODES + 3) / 4, 256, 0, stream>>>(row_ptr, col_idx, Z + 256, Z);
    gemm_mfma<0, 1, 0, 0, 12><<<GB, 512, 0, stream>>>(
        N_NODES, Z, ZPITCH, WfC, b2eff, out, HID, stats + 256);

    // BN2 + row normalize
    bn_params<<<1, 128, 0, stream>>>(stats + 256, g2, be2, scale2, shift2, 1.f / N_NODES);
    bn_rownorm<<<(N_NODES + 3) / 4, 256, 0, stream>>>(out, scale2, shift2);
}